// Round 5
// baseline (92.657 us; speedup 1.0000x reference)
//
#include <hip/hip_runtime.h>
#include <hip/hip_bf16.h>
#include <float.h>
#include <math.h>

#define BB 64
#define T1 33
#define TT 32
#define II 197
#define CC 512
#define TEMP 0.07f

typedef float f32x4 __attribute__((ext_vector_type(4)));
typedef int i32x4 __attribute__((ext_vector_type(4)));
typedef int i32x8 __attribute__((ext_vector_type(8)));

// ---- workspace layout (bytes) ----
// Frag records for mfma_scale_f32_16x16x128_f8f6f4 (fp8): per frag per kstep,
// 2048 B = [half h 0..1][lane 0..63][16 B]; element (row/col = lane&15,
// k = ks*128 + (lane>>4)*32 + h*16 + j).
// tl8: [xc8 8][ks 4][fa 16] records  (1 MB)   A: text rows r=fa*16+(lane&15)
// ve8: [y 64][ks 4][fb 16] records  (8 MB)   B: cols  i=fb*16+(lane&15); fb<=12 written
// tti: [64 x][64 y] f32
#define TL_OFF  0
#define VE_OFF  (1 << 20)                  // 1 MB
#define TTI_OFF ((1 << 20) + (8 << 20))    // 9 MB
#define KS_STRIDE   32768                  // 16 frags * 2048
#define GRP_STRIDE  131072                 // 4 ks * KS_STRIDE

// grid (64, 8): hz 0..3 = video c-chunks (= ksteps), hz 4..7 = text c-chunks.
// 512 threads. Pass 1 caches the block's 100 KB row-chunk in LDS (f32,
// stride 132 floats = 16-B aligned); pass 2 reads LDS, not global: inputs
// are read from HBM exactly once, and the old strided 64-B global reads
// (64 transactions/instr) are gone.
__global__ __launch_bounds__(512) void norm_all_kernel(const float* __restrict__ text,
                                                       const float* __restrict__ video,
                                                       unsigned char* __restrict__ tl8,
                                                       unsigned char* __restrict__ ve8) {
  int b = blockIdx.x, hz = blockIdx.y, tid = threadIdx.x;
  bool isV = hz < 4;
  int h2 = isV ? hz : hz - 4;                  // kstep
  const float* src = isV ? (video + (size_t)b * II * CC) : (text + (size_t)b * T1 * CC);
  int n = isV ? II : T1;

  __shared__ float cache[II][132];   // 104 KB: rows x 128-float chunk (pad 4)
  __shared__ float red[16][128];     // 8 KB
  __shared__ float rn[128];

  // pass 1: coalesced chunk read -> LDS cache + sum of squares over rows
  {
    int c4 = tid & 31, rg = tid >> 5;          // rg 0..15
    const float* p = src + h2 * 128 + c4 * 4;
    float4 s = {0.f, 0.f, 0.f, 0.f};
    for (int i = rg; i < n; i += 16) {
      float4 v = *(const float4*)(p + (size_t)i * CC);
      *(float4*)&cache[i][c4 * 4] = v;
      s.x += v.x * v.x; s.y += v.y * v.y; s.z += v.z * v.z; s.w += v.w * v.w;
    }
    *(float4*)&red[rg][c4 * 4] = s;
  }
  __syncthreads();
  if (tid < 128) {
    float s = 0.f;
#pragma unroll
    for (int g = 0; g < 16; ++g) s += red[g][tid];
    rn[tid] = 1.0f / sqrtf(s);
  }
  __syncthreads();

  // pass 2: build 16-B record slices from the LDS cache, fp8 e4m3.
  // slice (frag f, half h, lane l): row/col = f*16+(l&15),
  // chunk-local channels = (l>>4)*32 + h*16 + {0..15}
  if (isV) {
    for (int S = tid; S < 13 * 128; S += 512) {
      int fb = S >> 7, h = (S >> 6) & 1, lane = S & 63;
      int i = fb * 16 + (lane & 15);
      int kloc = ((lane >> 4) & 3) * 32 + h * 16;
      unsigned int wd[4];
#pragma unroll
      for (int q = 0; q < 4; ++q) {
        f32x4 u = {0.f, 0.f, 0.f, 0.f};
        if (i < II) u = *(const f32x4*)&cache[i][kloc + q * 4];
        f32x4 r = *(const f32x4*)&rn[kloc + q * 4];
        int wv = __builtin_amdgcn_cvt_pk_fp8_f32(u[0] * r[0], u[1] * r[1], 0, 0);
        wv = __builtin_amdgcn_cvt_pk_fp8_f32(u[2] * r[2], u[3] * r[3], wv, 1);
        wd[q] = (unsigned int)wv;
      }
      unsigned char* dst = ve8 + (size_t)b * GRP_STRIDE + h2 * KS_STRIDE +
                           fb * 2048 + h * 1024 + lane * 16;
      *(uint4*)dst = make_uint4(wd[0], wd[1], wd[2], wd[3]);
    }
  } else if (tid < 256) {
    // 2 fa_local x 2 h x 64 lane = 256 slices
    int fa_local = tid >> 7, h = (tid >> 6) & 1, lane = tid & 63;
    int t = fa_local * 16 + (lane & 15);          // 0..31
    int kloc = ((lane >> 4) & 3) * 32 + h * 16;
    unsigned int wd[4];
#pragma unroll
    for (int q = 0; q < 4; ++q) {
      f32x4 u = *(const f32x4*)&cache[1 + t][kloc + q * 4];
      f32x4 r = *(const f32x4*)&rn[kloc + q * 4];
      int wv = __builtin_amdgcn_cvt_pk_fp8_f32(u[0] * r[0], u[1] * r[1], 0, 0);
      wv = __builtin_amdgcn_cvt_pk_fp8_f32(u[2] * r[2], u[3] * r[3], wv, 1);
      wd[q] = (unsigned int)wv;
    }
    int fa = (b & 7) * 2 + fa_local;
    unsigned char* dst = tl8 + (size_t)(b >> 3) * GRP_STRIDE + h2 * KS_STRIDE +
                         fa * 2048 + h * 1024 + lane * 16;
    *(uint4*)dst = make_uint4(wd[0], wd[1], wd[2], wd[3]);
  }
}

typedef __attribute__((address_space(3))) unsigned int lds_u32;
typedef __attribute__((address_space(1))) const unsigned int glb_u32;
__device__ __forceinline__ void gl16(const unsigned char* g, unsigned char* l) {
  __builtin_amdgcn_global_load_lds((glb_u32*)(const void*)g, (lds_u32*)(void*)l, 16, 0, 0);
}

// 1024 blocks x 512 threads, 2 blocks/CU (80 KB LDS exactly: A 8 frags +
// B 12 frags staged, ring-2; smax overlaid on As after the K-loop; B frag 12
// loaded direct-to-reg double-buffered by the wn==0 waves). 16 waves/CU =
// 4/SIMD: co-resident block + waves hide the depth-1 vmcnt drain that the
// old 1-block/CU ring-3 exposed. Compute identical to round 4 (mfma_scale
// 16x16x128 fp8, scales=1.0, col-frag f -> wave wn=f%4).
__global__ __launch_bounds__(512, 4) void sim_kernel(const unsigned char* __restrict__ tl8,
                                                     const unsigned char* __restrict__ ve8,
                                                     const int* __restrict__ mask,
                                                     float* __restrict__ tti) {
  int L = blockIdx.x;
  int xcd = L & 7;
  int idx = L >> 3;              // 0..127
  int y = xcd * 8 + (idx & 7);   // each XCD owns 8 consecutive y's
  int xcb = idx >> 3;            // 0..15 : 4 batch-x per block

  int tid = threadIdx.x;
  int w = tid >> 6, lane = tid & 63;
  int wm = w >> 2;               // 0..1 : rows wm*64..+64 (4 frags)
  int wn = w & 3;                // col frags wn, wn+4, wn+8 (+12 direct if wn==0)

  __shared__ __attribute__((aligned(16))) unsigned char As[2][8 * 2048];   // 32KB
  __shared__ __attribute__((aligned(16))) unsigned char Bs[2][12 * 2048];  // 48KB
  float* smax = (float*)&As[0][0];   // overlaid post-loop (2 KB)

  const unsigned char* Abase =
      tl8 + (size_t)(xcb >> 1) * GRP_STRIDE + (size_t)(xcb & 1) * 8 * 2048;
  const unsigned char* Bbase = ve8 + (size_t)y * GRP_STRIDE;

  // 40 gl16 units per kstep: 0..15 = A (fa=u>>1, h=u&1), 16..39 = B frags 0..11.
#define STG(s_) do {                                                          \
    int slot_ = (s_) & 1;                                                     \
    _Pragma("unroll")                                                         \
    for (int r_ = 0; r_ < 5; ++r_) {                                          \
      int g_ = w * 5 + r_;                                                    \
      if (g_ < 16) {                                                          \
        int fa_ = g_ >> 1, h_ = g_ & 1;                                       \
        const unsigned char* src_ =                                           \
            Abase + (size_t)(s_) * KS_STRIDE + fa_ * 2048 + h_ * 1024 + lane * 16; \
        gl16(src_, &As[slot_][(fa_ * 2 + h_) * 1024 + lane * 16]);            \
      } else {                                                                \
        int gb_ = g_ - 16;                                                    \
        int fb_ = gb_ >> 1, h_ = gb_ & 1;                                     \
        const unsigned char* src_ =                                           \
            Bbase + (size_t)(s_) * KS_STRIDE + fb_ * 2048 + h_ * 1024 + lane * 16; \
        gl16(src_, &Bs[slot_][(fb_ * 2 + h_) * 1024 + lane * 16]);            \
      }                                                                       \
    }                                                                         \
  } while (0)

#define LD12(s_, dst_) do {                                                   \
    const unsigned char* p_ = Bbase + (size_t)(s_) * KS_STRIDE + 12 * 2048 + lane * 16; \
    dst_##h0 = *(const i32x4*)(p_);                                           \
    dst_##h1 = *(const i32x4*)(p_ + 1024);                                    \
  } while (0)

  // KCOMPUTE: slot_ = LDS slot; F12_: 0 = none, 1 = use fr A regs, 2 = use fr B regs
#define KCOMPUTE(slot_, F12_) do {                                            \
    i32x8 aop_[4];                                                            \
    _Pragma("unroll")                                                         \
    for (int ma_ = 0; ma_ < 4; ++ma_) {                                       \
      i32x4 h0_ = *(const i32x4*)&As[slot_][((wm * 4 + ma_) * 2) * 1024 + lane * 16]; \
      i32x4 h1_ = *(const i32x4*)&As[slot_][((wm * 4 + ma_) * 2 + 1) * 1024 + lane * 16]; \
      aop_[ma_] = __builtin_shufflevector(h0_, h1_, 0, 1, 2, 3, 4, 5, 6, 7);  \
    }                                                                         \
    int nf_ = (F12_) ? 4 : 3;                                                 \
    i32x8 bop_[4];                                                            \
    _Pragma("unroll")                                                         \
    for (int nb_ = 0; nb_ < 3; ++nb_) {                                       \
      int fb_ = wn + 4 * nb_;                                                 \
      i32x4 h0_ = *(const i32x4*)&Bs[slot_][(fb_ * 2) * 1024 + lane * 16];    \
      i32x4 h1_ = *(const i32x4*)&Bs[slot_][(fb_ * 2 + 1) * 1024 + lane * 16]; \
      bop_[nb_] = __builtin_shufflevector(h0_, h1_, 0, 1, 2, 3, 4, 5, 6, 7);  \
    }                                                                         \
    if ((F12_) == 1) bop_[3] = __builtin_shufflevector(frAh0, frAh1, 0, 1, 2, 3, 4, 5, 6, 7); \
    if ((F12_) == 2) bop_[3] = __builtin_shufflevector(frBh0, frBh1, 0, 1, 2, 3, 4, 5, 6, 7); \
    __builtin_amdgcn_s_setprio(1);                                            \
    _Pragma("unroll")                                                         \
    for (int ma_ = 0; ma_ < 4; ++ma_)                                         \
      _Pragma("unroll")                                                       \
      for (int nb_ = 0; nb_ < 4; ++nb_)                                       \
        if (nb_ < nf_)                                                        \
          acc[ma_][nb_] = __builtin_amdgcn_mfma_scale_f32_16x16x128_f8f6f4(   \
              aop_[ma_], bop_[nb_], acc[ma_][nb_], 0, 0,                      \
              0, 0x7F7F7F7F, 0, 0x7F7F7F7F);                                  \
    __builtin_amdgcn_s_setprio(0);                                            \
  } while (0)

  f32x4 acc[4][4] = {};
  i32x4 frAh0, frAh1, frBh0, frBh1;   // frag-12 double buffer (wn==0 only)

  // prologue: kstep 0 staged; wn==0 also loads frag12(0) into buf A
  STG(0);
  if (wn == 0) LD12(0, frA);
  asm volatile("s_waitcnt vmcnt(0)" ::: "memory");
  __builtin_amdgcn_s_barrier();

  // s=0: compute slot0 (frag12 buf A), stage kstep1, load frag12(1)->buf B
  STG(1);
  if (wn == 0) {
    LD12(1, frB);
    KCOMPUTE(0, 1);
    asm volatile("s_waitcnt vmcnt(2)" ::: "memory");  // STG(1) done; frB may fly
  } else {
    KCOMPUTE(0, 0);
    asm volatile("s_waitcnt vmcnt(0)" ::: "memory");
  }
  __builtin_amdgcn_s_barrier();

  // s=1: compute slot1 (buf B), stage kstep2, load frag12(2)->buf A
  STG(0 + 2 - 2);  // writes slot (2&1)=0: STG(2)
#undef STG
#define STG2(s_, slot_) do {                                                  \
    _Pragma("unroll")                                                         \
    for (int r_ = 0; r_ < 5; ++r_) {                                          \
      int g_ = w * 5 + r_;                                                    \
      if (g_ < 16) {                                                          \
        int fa_ = g_ >> 1, h_ = g_ & 1;                                       \
        const unsigned char* src_ =                                           \
            Abase + (size_t)(s_) * KS_STRIDE + fa_ * 2048 + h_ * 1024 + lane * 16; \
        gl16(src_, &As[slot_][(fa_ * 2 + h_) * 1024 + lane * 16]);            \
      } else {                                                                \
        int gb_ = g_ - 16;                                                    \
        int fb_ = gb_ >> 1, h_ = gb_ & 1;                                     \
        const unsigned char* src_ =                                           \
            Bbase + (size_t)(s_) * KS_STRIDE + fb_ * 2048 + h_ * 1024 + lane * 16; \
        gl16(src_, &Bs[slot_][(fb_ * 2 + h_) * 1024 + lane * 16]);            \
      }                                                                       \
    }                                                                         \
  } while (0)
  if (wn == 0) {
    LD12(2, frA);
    KCOMPUTE(1, 2);
    asm volatile("s_waitcnt vmcnt(2)" ::: "memory");
  } else {
    KCOMPUTE(1, 0);
    asm volatile("s_waitcnt vmcnt(0)" ::: "memory");
  }
  __builtin_amdgcn_s_barrier();

  // s=2: compute slot0 (buf A), stage kstep3, load frag12(3)->buf B
  STG2(3, 1);
  if (wn == 0) {
    LD12(3, frB);
    KCOMPUTE(0, 1);
    asm volatile("s_waitcnt vmcnt(2)" ::: "memory");
  } else {
    KCOMPUTE(0, 0);
    asm volatile("s_waitcnt vmcnt(0)" ::: "memory");
  }
  __builtin_amdgcn_s_barrier();

  // s=3: compute slot1 (buf B); nothing to stage
  if (wn == 0) KCOMPUTE(1, 2);
  else         KCOMPUTE(1, 0);
#undef STG2
#undef LD12
#undef KCOMPUTE

  // ---- fused epilogue: max over i (i<197), masked mean over t -> tti ----
  int col = lane & 15, gq = lane >> 4;
  int nfrag = (wn == 0) ? 4 : 3;
  bool valid[4];
#pragma unroll
  for (int nb = 0; nb < 4; ++nb) {
    int fb = wn + 4 * nb;
    valid[nb] = (nb < nfrag) && (fb * 16 + col < II);
  }

  float mx[4][4];
#pragma unroll
  for (int ma = 0; ma < 4; ++ma)
#pragma unroll
    for (int reg = 0; reg < 4; ++reg) {
      float m = -FLT_MAX;
#pragma unroll
      for (int nb = 0; nb < 4; ++nb)
        if (valid[nb]) m = fmaxf(m, acc[ma][nb][reg]);
      mx[ma][reg] = m;
    }
#pragma unroll
  for (int st = 1; st <= 8; st <<= 1)
#pragma unroll
    for (int ma = 0; ma < 4; ++ma)
#pragma unroll
      for (int reg = 0; reg < 4; ++reg)
        mx[ma][reg] = fmaxf(mx[ma][reg], __shfl_xor(mx[ma][reg], st));

  __syncthreads();   // all waves done with As slot0 before smax overlay
  if (col == 0) {
#pragma unroll
    for (int ma = 0; ma < 4; ++ma)
#pragma unroll
      for (int reg = 0; reg < 4; ++reg)
        smax[wn * 128 + wm * 64 + ma * 16 + gq * 4 + reg] = mx[ma][reg];
  }
  __syncthreads();

  if (tid < 128) {
    int r = tid;                       // row = x_local*32 + t
    float m = fmaxf(fmaxf(smax[r], smax[128 + r]),
                    fmaxf(smax[256 + r], smax[384 + r]));
    int x = xcb * 4 + (r >> 5), tt = r & 31;
    int mk = mask[x * T1 + 1 + tt];
    float num = mk ? m * TEMP : 0.f;
    float cnt = mk ? 1.f : 0.f;
#pragma unroll
    for (int st = 1; st < 32; st <<= 1) {
      num += __shfl_xor(num, st);
      cnt += __shfl_xor(cnt, st);
    }
    if (tt == 0) tti[x * 64 + y] = num / fmaxf(cnt, 1e-6f);
  }
}

// 1 block x 1024 threads: 16 threads per row x, each sums 4 y's.
__global__ void loss_kernel(const float* __restrict__ tti, float* __restrict__ out) {
  __shared__ float lxs[64];
  int tid = threadIdx.x;
  int x = tid >> 4, q = tid & 15;
  float4 v = *(const float4*)&tti[x * 64 + q * 4];
  float den = expf(v.x) + expf(v.y) + expf(v.z) + expf(v.w);
#pragma unroll
  for (int st = 1; st < 16; st <<= 1) den += __shfl_xor(den, st);
  if (q == 0) {
    float pos = expf(tti[x * 64 + x]);
    lxs[x] = -logf(pos / den + 1e-20f);
  }
  __syncthreads();
  if (tid < 64) {
    float lx = lxs[tid];
#pragma unroll
    for (int s = 1; s < 64; s <<= 1) lx += __shfl_xor(lx, s);
    if (tid == 0) out[0] = lx * (1.0f / 64.0f);
  }
}

extern "C" void kernel_launch(void* const* d_in, const int* in_sizes, int n_in,
                              void* d_out, int out_size, void* d_ws, size_t ws_size,
                              hipStream_t stream) {
  const float* text = (const float*)d_in[0];   // [64][33][512] f32
  const float* video = (const float*)d_in[1];  // [64][197][512] f32
  const int* mask = (const int*)d_in[2];       // [64][33] i32
  float* out = (float*)d_out;

  char* ws = (char*)d_ws;
  unsigned char* tl8 = (unsigned char*)(ws + TL_OFF);
  unsigned char* ve8 = (unsigned char*)(ws + VE_OFF);
  float* tti = (float*)(ws + TTI_OFF);

  hipLaunchKernelGGL(norm_all_kernel, dim3(BB, 8), dim3(512), 0, stream, text, video, tl8, ve8);
  hipLaunchKernelGGL(sim_kernel, dim3(1024), dim3(512), 0, stream, tl8, ve8, mask, tti);
  hipLaunchKernelGGL(loss_kernel, dim3(1), dim3(1024), 0, stream, tti, out);
}

// Round 6
// 45.966 us; speedup vs baseline: 2.0158x; 2.0158x over previous
//
#include <hip/hip_runtime.h>
#include <hip/hip_bf16.h>
#include <float.h>
#include <math.h>

#define BB 64
#define T1 33
#define TT 32
#define II 197
#define CC 512
#define TEMP 0.07f

typedef float f32x4 __attribute__((ext_vector_type(4)));
typedef int i32x4 __attribute__((ext_vector_type(4)));
typedef int i32x8 __attribute__((ext_vector_type(8)));

// ---- workspace layout (bytes) ----
// Frag records for mfma_scale_f32_16x16x128_f8f6f4 (fp8): per frag per kstep,
// 2048 B = [half h 0..1][lane 0..63][16 B]; element (row/col = lane&15,
// k = ks*128 + (lane>>4)*32 + h*16 + j).
// tl8: [xc8 8][ks 4][fa 16] records  (1 MB)   A: text rows r=fa*16+(lane&15)
// ve8: [y 64][ks 4][fb 16] records  (8 MB)   B: cols  i=fb*16+(lane&15); fb<=12 written
// tti: [64 x][64 y] f32
#define TL_OFF  0
#define VE_OFF  (1 << 20)                  // 1 MB
#define TTI_OFF ((1 << 20) + (8 << 20))    // 9 MB
#define KS_STRIDE   32768                  // 16 frags * 2048
#define GRP_STRIDE  131072                 // 4 ks * KS_STRIDE

// grid (64, 8): hz 0..3 = video c-chunks (= ksteps), hz 4..7 = text c-chunks.
// 512 threads. Pass 1 caches the block's 100 KB row-chunk in LDS; pass 2
// builds fp8 records from LDS (inputs read from HBM exactly once, coalesced).
__global__ __launch_bounds__(512) void norm_all_kernel(const float* __restrict__ text,
                                                       const float* __restrict__ video,
                                                       unsigned char* __restrict__ tl8,
                                                       unsigned char* __restrict__ ve8) {
  int b = blockIdx.x, hz = blockIdx.y, tid = threadIdx.x;
  bool isV = hz < 4;
  int h2 = isV ? hz : hz - 4;                  // kstep
  const float* src = isV ? (video + (size_t)b * II * CC) : (text + (size_t)b * T1 * CC);
  int n = isV ? II : T1;

  __shared__ float cache[II][132];   // 104 KB: rows x 128-float chunk (pad 4)
  __shared__ float red[16][128];     // 8 KB
  __shared__ float rn[128];

  // pass 1: coalesced chunk read -> LDS cache + sum of squares over rows
  {
    int c4 = tid & 31, rg = tid >> 5;          // rg 0..15
    const float* p = src + h2 * 128 + c4 * 4;
    float4 s = {0.f, 0.f, 0.f, 0.f};
    for (int i = rg; i < n; i += 16) {
      float4 v = *(const float4*)(p + (size_t)i * CC);
      *(float4*)&cache[i][c4 * 4] = v;
      s.x += v.x * v.x; s.y += v.y * v.y; s.z += v.z * v.z; s.w += v.w * v.w;
    }
    *(float4*)&red[rg][c4 * 4] = s;
  }
  __syncthreads();
  if (tid < 128) {
    float s = 0.f;
#pragma unroll
    for (int g = 0; g < 16; ++g) s += red[g][tid];
    rn[tid] = 1.0f / sqrtf(s);
  }
  __syncthreads();

  // pass 2: build 16-B record slices from the LDS cache, fp8 e4m3.
  // slice (frag f, half h, lane l): row/col = f*16+(l&15),
  // chunk-local channels = (l>>4)*32 + h*16 + {0..15}
  if (isV) {
    for (int S = tid; S < 13 * 128; S += 512) {
      int fb = S >> 7, h = (S >> 6) & 1, lane = S & 63;
      int i = fb * 16 + (lane & 15);
      int kloc = ((lane >> 4) & 3) * 32 + h * 16;
      unsigned int wd[4];
#pragma unroll
      for (int q = 0; q < 4; ++q) {
        f32x4 u = {0.f, 0.f, 0.f, 0.f};
        if (i < II) u = *(const f32x4*)&cache[i][kloc + q * 4];
        f32x4 r = *(const f32x4*)&rn[kloc + q * 4];
        int wv = __builtin_amdgcn_cvt_pk_fp8_f32(u[0] * r[0], u[1] * r[1], 0, 0);
        wv = __builtin_amdgcn_cvt_pk_fp8_f32(u[2] * r[2], u[3] * r[3], wv, 1);
        wd[q] = (unsigned int)wv;
      }
      unsigned char* dst = ve8 + (size_t)b * GRP_STRIDE + h2 * KS_STRIDE +
                           fb * 2048 + h * 1024 + lane * 16;
      *(uint4*)dst = make_uint4(wd[0], wd[1], wd[2], wd[3]);
    }
  } else if (tid < 256) {
    // 2 fa_local x 2 h x 64 lane = 256 slices
    int fa_local = tid >> 7, h = (tid >> 6) & 1, lane = tid & 63;
    int t = fa_local * 16 + (lane & 15);          // 0..31
    int kloc = ((lane >> 4) & 3) * 32 + h * 16;
    unsigned int wd[4];
#pragma unroll
    for (int q = 0; q < 4; ++q) {
      f32x4 u = *(const f32x4*)&cache[1 + t][kloc + q * 4];
      f32x4 r = *(const f32x4*)&rn[kloc + q * 4];
      int wv = __builtin_amdgcn_cvt_pk_fp8_f32(u[0] * r[0], u[1] * r[1], 0, 0);
      wv = __builtin_amdgcn_cvt_pk_fp8_f32(u[2] * r[2], u[3] * r[3], wv, 1);
      wd[q] = (unsigned int)wv;
    }
    int fa = (b & 7) * 2 + fa_local;
    unsigned char* dst = tl8 + (size_t)(b >> 3) * GRP_STRIDE + h2 * KS_STRIDE +
                         fa * 2048 + h * 1024 + lane * 16;
    *(uint4*)dst = make_uint4(wd[0], wd[1], wd[2], wd[3]);
  }
}

typedef __attribute__((address_space(3))) unsigned int lds_u32;
typedef __attribute__((address_space(1))) const unsigned int glb_u32;
__device__ __forceinline__ void gl16(const unsigned char* g, unsigned char* l) {
  __builtin_amdgcn_global_load_lds((glb_u32*)(const void*)g, (lds_u32*)(void*)l, 16, 0, 0);
}

// ROUND-4 sim_kernel, verbatim (verified: FETCH 16.5 MB, WRITE 0.16 MB, no
// spills). 1024 blocks x 512 threads, 1 block/CU (146 KB LDS), launch_bounds
// (512,2) -> 256-VGPR cap, NO spilling (round 5's (512,4) cap of 128 spilled
// acc: 230 MB scratch writes). K=512 as 4 ksteps of 128 via mfma_scale
// 16x16x128 fp8 (scales=1.0). Ring-3 kstep slots, prefetch depth 2, uniform
// 6 gl16/wave/kstep, vmcnt(6) steady / vmcnt(0) once. Col-frag f -> wave
// wn=f%4 (4/3/3/3 SIMD-balanced). setprio around MFMA.
__global__ __launch_bounds__(512, 2) void sim_kernel(const unsigned char* __restrict__ tl8,
                                                     const unsigned char* __restrict__ ve8,
                                                     const int* __restrict__ mask,
                                                     float* __restrict__ tti) {
  int L = blockIdx.x;
  int xcd = L & 7;
  int idx = L >> 3;              // 0..127
  int y = xcd * 8 + (idx & 7);   // each XCD owns 8 consecutive y's
  int xcb = idx >> 3;            // 0..15 : 4 batch-x per block

  int tid = threadIdx.x;
  int w = tid >> 6, lane = tid & 63;
  int wm = w >> 2;               // 0..1 : rows wm*64..+64 (4 frags)
  int wn = w & 3;                // col frags wn, wn+4, wn+8 (+12 if wn==0)

  __shared__ __attribute__((aligned(16))) unsigned char As[3][8 * 2048];   // 48KB
  __shared__ __attribute__((aligned(16))) unsigned char Bs[3][16 * 2048];  // 96KB
  __shared__ float smax[4 * 128];                                          // 2KB

  const unsigned char* Abase =
      tl8 + (size_t)(xcb >> 1) * GRP_STRIDE + (size_t)(xcb & 1) * 8 * 2048;
  const unsigned char* Bbase = ve8 + (size_t)y * GRP_STRIDE;

  // 48 gl16 units per kstep: 0..15 = A (fa_rel=u>>1, h=u&1), 16..47 = B.
#define STG(s_) do {                                                          \
    int slot_ = (s_) % 3;                                                     \
    _Pragma("unroll")                                                         \
    for (int r_ = 0; r_ < 6; ++r_) {                                          \
      int g_ = w * 6 + r_;                                                    \
      if (g_ < 16) {                                                          \
        int fa_ = g_ >> 1, h_ = g_ & 1;                                       \
        const unsigned char* src_ =                                           \
            Abase + (size_t)(s_) * KS_STRIDE + fa_ * 2048 + h_ * 1024 + lane * 16; \
        gl16(src_, &As[slot_][(fa_ * 2 + h_) * 1024 + lane * 16]);            \
      } else {                                                                \
        int gb_ = g_ - 16;                                                    \
        int fb_ = gb_ >> 1, h_ = gb_ & 1;                                     \
        const unsigned char* src_ =                                           \
            Bbase + (size_t)(s_) * KS_STRIDE + fb_ * 2048 + h_ * 1024 + lane * 16; \
        gl16(src_, &Bs[slot_][(fb_ * 2 + h_) * 1024 + lane * 16]);            \
      }                                                                       \
    }                                                                         \
  } while (0)

#define KCOMPUTE(slot_, NF_) do {                                             \
    i32x8 aop_[4];                                                            \
    _Pragma("unroll")                                                         \
    for (int ma_ = 0; ma_ < 4; ++ma_) {                                       \
      i32x4 h0_ = *(const i32x4*)&As[slot_][((wm * 4 + ma_) * 2) * 1024 + lane * 16]; \
      i32x4 h1_ = *(const i32x4*)&As[slot_][((wm * 4 + ma_) * 2 + 1) * 1024 + lane * 16]; \
      aop_[ma_] = __builtin_shufflevector(h0_, h1_, 0, 1, 2, 3, 4, 5, 6, 7);  \
    }                                                                         \
    i32x8 bop_[NF_];                                                          \
    _Pragma("unroll")                                                         \
    for (int nb_ = 0; nb_ < NF_; ++nb_) {                                     \
      int fb_ = wn + 4 * nb_;                                                 \
      i32x4 h0_ = *(const i32x4*)&Bs[slot_][(fb_ * 2) * 1024 + lane * 16];    \
      i32x4 h1_ = *(const i32x4*)&Bs[slot_][(fb_ * 2 + 1) * 1024 + lane * 16]; \
      bop_[nb_] = __builtin_shufflevector(h0_, h1_, 0, 1, 2, 3, 4, 5, 6, 7);  \
    }                                                                         \
    __builtin_amdgcn_s_setprio(1);                                            \
    _Pragma("unroll")                                                         \
    for (int ma_ = 0; ma_ < 4; ++ma_)                                         \
      _Pragma("unroll")                                                       \
      for (int nb_ = 0; nb_ < NF_; ++nb_)                                     \
        acc[ma_][nb_] = __builtin_amdgcn_mfma_scale_f32_16x16x128_f8f6f4(     \
            aop_[ma_], bop_[nb_], acc[ma_][nb_], 0, 0,                        \
            0, 0x7F7F7F7F, 0, 0x7F7F7F7F);                                    \
    __builtin_amdgcn_s_setprio(0);                                            \
  } while (0)

  f32x4 acc[4][4] = {};

  STG(0); STG(1);
  asm volatile("s_waitcnt vmcnt(6)" ::: "memory");
  __builtin_amdgcn_s_barrier();

  // s=0
  STG(2);
  if (wn == 0) KCOMPUTE(0, 4); else KCOMPUTE(0, 3);
  asm volatile("s_waitcnt vmcnt(6)" ::: "memory");
  __builtin_amdgcn_s_barrier();
  // s=1
  STG(3);
  if (wn == 0) KCOMPUTE(1, 4); else KCOMPUTE(1, 3);
  asm volatile("s_waitcnt vmcnt(6)" ::: "memory");
  __builtin_amdgcn_s_barrier();
  // s=2
  if (wn == 0) KCOMPUTE(2, 4); else KCOMPUTE(2, 3);
  asm volatile("s_waitcnt vmcnt(0)" ::: "memory");
  __builtin_amdgcn_s_barrier();
  // s=3
  if (wn == 0) KCOMPUTE(0, 4); else KCOMPUTE(0, 3);
#undef STG
#undef KCOMPUTE

  // ---- fused epilogue: max over i (i<197), masked mean over t -> tti ----
  int col = lane & 15, gq = lane >> 4;
  int nfrag = (wn == 0) ? 4 : 3;
  bool valid[4];
#pragma unroll
  for (int nb = 0; nb < 4; ++nb) {
    int fb = wn + 4 * nb;
    valid[nb] = (nb < nfrag) && (fb * 16 + col < II);
  }

  float mx[4][4];
#pragma unroll
  for (int ma = 0; ma < 4; ++ma)
#pragma unroll
    for (int reg = 0; reg < 4; ++reg) {
      float m = -FLT_MAX;
#pragma unroll
      for (int nb = 0; nb < 4; ++nb)
        if (valid[nb]) m = fmaxf(m, acc[ma][nb][reg]);
      mx[ma][reg] = m;
    }
#pragma unroll
  for (int st = 1; st <= 8; st <<= 1)
#pragma unroll
    for (int ma = 0; ma < 4; ++ma)
#pragma unroll
      for (int reg = 0; reg < 4; ++reg)
        mx[ma][reg] = fmaxf(mx[ma][reg], __shfl_xor(mx[ma][reg], st));

  if (col == 0) {
#pragma unroll
    for (int ma = 0; ma < 4; ++ma)
#pragma unroll
      for (int reg = 0; reg < 4; ++reg)
        smax[wn * 128 + wm * 64 + ma * 16 + gq * 4 + reg] = mx[ma][reg];
  }
  __syncthreads();

  if (tid < 128) {
    int r = tid;                       // row = x_local*32 + t
    float m = fmaxf(fmaxf(smax[r], smax[128 + r]),
                    fmaxf(smax[256 + r], smax[384 + r]));
    int x = xcb * 4 + (r >> 5), tt = r & 31;
    int mk = mask[x * T1 + 1 + tt];
    float num = mk ? m * TEMP : 0.f;
    float cnt = mk ? 1.f : 0.f;
#pragma unroll
    for (int st = 1; st < 32; st <<= 1) {
      num += __shfl_xor(num, st);
      cnt += __shfl_xor(cnt, st);
    }
    if (tt == 0) tti[x * 64 + y] = num / fmaxf(cnt, 1e-6f);
  }
}

// 1 block x 1024 threads: 16 threads per row x, each sums 4 y's.
__global__ void loss_kernel(const float* __restrict__ tti, float* __restrict__ out) {
  __shared__ float lxs[64];
  int tid = threadIdx.x;
  int x = tid >> 4, q = tid & 15;
  float4 v = *(const float4*)&tti[x * 64 + q * 4];
  float den = expf(v.x) + expf(v.y) + expf(v.z) + expf(v.w);
#pragma unroll
  for (int st = 1; st < 16; st <<= 1) den += __shfl_xor(den, st);
  if (q == 0) {
    float pos = expf(tti[x * 64 + x]);
    lxs[x] = -logf(pos / den + 1e-20f);
  }
  __syncthreads();
  if (tid < 64) {
    float lx = lxs[tid];
#pragma unroll
    for (int s = 1; s < 64; s <<= 1) lx += __shfl_xor(lx, s);
    if (tid == 0) out[0] = lx * (1.0f / 64.0f);
  }
}

extern "C" void kernel_launch(void* const* d_in, const int* in_sizes, int n_in,
                              void* d_out, int out_size, void* d_ws, size_t ws_size,
                              hipStream_t stream) {
  const float* text = (const float*)d_in[0];   // [64][33][512] f32
  const float* video = (const float*)d_in[1];  // [64][197][512] f32
  const int* mask = (const int*)d_in[2];       // [64][33] i32
  float* out = (float*)d_out;

  char* ws = (char*)d_ws;
  unsigned char* tl8 = (unsigned char*)(ws + TL_OFF);
  unsigned char* ve8 = (unsigned char*)(ws + VE_OFF);
  float* tti = (float*)(ws + TTI_OFF);

  hipLaunchKernelGGL(norm_all_kernel, dim3(BB, 8), dim3(512), 0, stream, text, video, tl8, ve8);
  hipLaunchKernelGGL(sim_kernel, dim3(1024), dim3(512), 0, stream, tl8, ve8, mask, tti);
  hipLaunchKernelGGL(loss_kernel, dim3(1), dim3(1024), 0, stream, tti, out);
}